// Round 8
// baseline (189.427 us; speedup 1.0000x reference)
//
#include <hip/hip_runtime.h>
#include <float.h>

#define NUM_EMB 512
#define DIM     128
#define HWX     4096          // 64*64 spatial per batch
#define NPOS    (32 * 4096)   // 131072 positions
#define EPS1    0.175f        // per-SCORE half of the validated 0.35 comparison budget

// ---------------- workspace layout (bytes) ----------------
#define WS_E16   ((size_t)0)                    // 512*128 fp16 = 131072
#define WS_ESQ   ((size_t)131072)               // 512 fp32     = 2048
#define WS_NEED  ((size_t)133120)

using half8 = __attribute__((ext_vector_type(8))) _Float16;
using f32x4 = __attribute__((ext_vector_type(4))) float;

// ---------------- prep: e16[k][c], exact e_sq ----------------
__global__ void prep_kernel(const float* __restrict__ emb, _Float16* __restrict__ e16,
                            float* __restrict__ esq) {
    int k = blockIdx.x * blockDim.x + threadIdx.x;
    if (k < NUM_EMB) {
        const float4* row = (const float4*)(emb + (size_t)k * DIM);
        _Float16* dst = e16 + (size_t)k * DIM;
        float s0 = 0.f, s1 = 0.f, s2 = 0.f, s3 = 0.f;
        #pragma unroll
        for (int c = 0; c < DIM / 4; ++c) {
            float4 v = row[c];
            s0 = fmaf(v.x, v.x, s0);
            s1 = fmaf(v.y, v.y, s1);
            s2 = fmaf(v.z, v.z, s2);
            s3 = fmaf(v.w, v.w, s3);
            dst[4 * c + 0] = (_Float16)v.x;
            dst[4 * c + 1] = (_Float16)v.y;
            dst[4 * c + 2] = (_Float16)v.z;
            dst[4 * c + 3] = (_Float16)v.w;
        }
        esq[k] = (s0 + s1) + (s2 + s3);   // identical math to round-1 (verified exact)
    }
}

// ---------------- gemm v12: v11 + AMORTIZED in-block rescan ------------------
// v11's rescan paid one full codebook pass PER FLAG (~2.5-3 us each: the emb
// reads are 64-line fan-outs per instruction, TA-serialized), mean ~6 flags ->
// +17 us. v12 stages up to 4 flagged z-rows into dead Ash LDS and makes ONE
// codebook pass per chunk: same serialized emb traffic feeds 4x the fma
// (32/c4 instead of 8), barriers 3/chunk instead of 3/flag. Per-dot fma chain
// (c4 ascending, x/y/z/w) bit-identical to the validated rescan; flag
// criterion (exact screen, EPS1) unchanged; K-loop/pair/epilogue untouched.
__global__ __launch_bounds__(256) void gemm_argmin(const float* __restrict__ z,
                                                   const _Float16* __restrict__ e16,
                                                   const float* __restrict__ esq,
                                                   const float* __restrict__ emb,
                                                   float* __restrict__ out) {
    __shared__ __align__(16) char Ash[128 * 272];   // A tile; pair-partials; zstage
    __shared__ float mB1[2][128];                   // ranking; mB1[1] reused as flist
    __shared__ float mB2[2][128];                   // ranking; reused as reduce scratch
    __shared__ float mB3[2][128];
    __shared__ float msh[128];                      // packed m3 per position
    __shared__ int   ish[128];
    __shared__ int   bcnt;

    int t = threadIdx.x;
    int lane = t & 63, wave = t >> 6;
    int wm = wave & 1, wn = wave >> 1;
    int quad = lane >> 4, l15 = lane & 15;
    int n0 = blockIdx.x * 128;
    int bb = n0 >> 12;
    int hw0 = n0 & 4095;          // block-aligned: same batch, contiguous 128 hw

    if (t == 0) bcnt = 0;

    // ---- prologue: 4 consecutive positions x 16 channels per thread, dwordx4
    {
        int g = t & 31, cq = t >> 5;
        int hw = hw0 + 4 * g;
        const float* zp = z + (size_t)bb * DIM * HWX + (size_t)cq * 16 * HWX + hw;
        char* arow0 = Ash + (4 * g) * 272;
        int xr = g & 7;                         // = (row>>2)&7 for rows 4g..4g+3
        #pragma unroll
        for (int k = 0; k < 2; ++k) {           // two 8-channel chunks
            float4 v[8];
            #pragma unroll
            for (int c = 0; c < 8; ++c)
                v[c] = *(const float4*)(zp + (size_t)(k * 8 + c) * HWX);
            int slotb = ((2 * cq + k) ^ xr) * 16;   // swizzled 16B slot
            #pragma unroll
            for (int j = 0; j < 4; ++j) {       // register 4x4 transpose -> row j
                half8 hv;
                #pragma unroll
                for (int c = 0; c < 8; ++c) {
                    float f = (j == 0) ? v[c].x : (j == 1) ? v[c].y
                            : (j == 2) ? v[c].z : v[c].w;
                    hv[c] = (_Float16)f;
                }
                *(half8*)(arow0 + j * 272 + slotb) = hv;
            }
        }
    }
    __syncthreads();   // the ONLY barrier before the ranking phase

    float b1[16], b2[16], b3[16];
    #pragma unroll
    for (int s = 0; s < 16; ++s) { b1[s] = 3.0e38f; b2[s] = 3.0e38f; b3[s] = 3.0e38f; }

    // A-fragment base: row = wm*64 + mt*16 + l15; swizzle folds to lane-const
    const char* abase = Ash + (wm * 64 + l15) * 272 + (quad ^ (l15 >> 2)) * 16;
    const char* ebase = (const char*)e16 + ((size_t)(wn * 32 + l15) << 8) + quad * 16;
    const float* eqb  = esq + wn * 32 + l15;

    for (int tile = 0; tile < 8; ++tile) {
        // ---- B fragments: 8 dwordx4 from L2-hot e16, issued together
        half8 bf[2][4];
        {
            const char* eb = ebase + (size_t)tile * 64 * 256;
            #pragma unroll
            for (int nt = 0; nt < 2; ++nt)
                #pragma unroll
                for (int kc = 0; kc < 4; ++kc)
                    bf[nt][kc] = *(const half8*)(eb + nt * 4096 + kc * 64);
        }
        float es0 = eqb[tile * 64];
        float es1 = eqb[tile * 64 + 16];

        f32x4 acc[4][2];
        #pragma unroll
        for (int mt = 0; mt < 4; ++mt)
            #pragma unroll
            for (int nt = 0; nt < 2; ++nt)
                acc[mt][nt] = (f32x4){0.f, 0.f, 0.f, 0.f};

        #pragma unroll
        for (int kc = 0; kc < 4; ++kc) {
            half8 af[4];
            #pragma unroll
            for (int mt = 0; mt < 4; ++mt)
                af[mt] = *(const half8*)(abase + mt * (16 * 272) + ((kc ^ (mt & 1)) * 64));
            #pragma unroll
            for (int mt = 0; mt < 4; ++mt)
                #pragma unroll
                for (int nt = 0; nt < 2; ++nt)
                    acc[mt][nt] = __builtin_amdgcn_mfma_f32_16x16x32_f16(af[mt], bf[nt][kc], acc[mt][nt], 0, 0, 0);
        }

        // ---- packed top-3: ~8 VALU/score, index rides in the low 9 bits
        #pragma unroll
        for (int nt = 0; nt < 2; ++nt) {
            unsigned code = (unsigned)(tile * 64 + wn * 32 + nt * 16 + l15);
            float es = nt ? es1 : es0;
            #pragma unroll
            for (int mt = 0; mt < 4; ++mt)
                #pragma unroll
                for (int r = 0; r < 4; ++r) {
                    int s = mt * 4 + r;
                    float sc = fmaf(-2.0f, acc[mt][nt][r], es);
                    float p = __uint_as_float((__float_as_uint(sc) & 0xFFFFFE00u) | code);
                    float t1 = fmaxf(b1[s], p);       // displaced from level 1
                    b1[s] = fminf(b1[s], p);
                    float t2 = fmaxf(b2[s], t1);      // displaced from level 2
                    b2[s] = fminf(b2[s], t1);
                    b3[s] = fminf(b3[s], t2);
                }
        }
    }

    // ---- butterfly top-3 merge across the 16 lanes (l15) sharing each position
    #pragma unroll
    for (int d = 1; d < 16; d <<= 1) {
        #pragma unroll
        for (int s = 0; s < 16; ++s) {
            float o1 = __shfl_xor(b1[s], d, 64);
            float o2 = __shfl_xor(b2[s], d, 64);
            float o3 = __shfl_xor(b3[s], d, 64);
            float u1 = fmaxf(b1[s], o1);
            b1[s] = fminf(b1[s], o1);
            float l2 = fminf(b2[s], o2);
            float w  = fmaxf(u1, l2);
            b2[s] = fminf(u1, l2);
            b3[s] = fminf(fminf(b3[s], o3), w);
        }
    }
    if (l15 == 0) {
        #pragma unroll
        for (int s = 0; s < 16; ++s) {
            int m = wm * 64 + (s >> 2) * 16 + quad * 4 + (s & 3);
            mB1[wn][m] = b1[s];
            mB2[wn][m] = b2[s];
            mB3[wn][m] = b3[s];
        }
    }
    __syncthreads();
    if (t < 128) {
        float a1 = mB1[0][t], c1 = mB1[1][t];
        float a2 = mB2[0][t], c2 = mB2[1][t];
        float a3 = mB3[0][t], c3 = mB3[1][t];
        float u1 = fmaxf(a1, c1);
        float m1 = fminf(a1, c1);
        float l2 = fminf(a2, c2);
        float m2 = fminf(u1, l2);
        float m3 = fminf(fminf(a3, c3), fmaxf(u1, l2));
        int ix1 = (int)(__float_as_uint(m1) & 511u);
        int ix2 = (int)(__float_as_uint(m2) & 511u);
        ish[t] = ix1 | (ix2 << 9);             // packed candidates for the pair phase
        msh[t] = m3;                           // packed 3rd-best for the exact screen
    }
    __syncthreads();

    // ---- fused pair phase: coalesced z re-read (L2/L3-hot), exact fp32 dots
    // with e_{i1}, e_{i2}; partials to a 9-float2-stride LDS overlay on Ash.
    {
        int g = t & 31, cq = t >> 5;
        int hw = hw0 + 4 * g;
        const float* zp = z + (size_t)bb * DIM * HWX + (size_t)cq * 16 * HWX + hw;
        int ii[4];
        #pragma unroll
        for (int j = 0; j < 4; ++j) ii[j] = ish[4 * g + j];
        float d1[4] = {0.f, 0.f, 0.f, 0.f};
        float d2[4] = {0.f, 0.f, 0.f, 0.f};
        #pragma unroll
        for (int k = 0; k < 2; ++k) {
            float4 v[8];
            #pragma unroll
            for (int c = 0; c < 8; ++c)
                v[c] = *(const float4*)(zp + (size_t)(k * 8 + c) * HWX);
            #pragma unroll
            for (int j = 0; j < 4; ++j) {
                const float* e1p = emb + (size_t)(ii[j] & 511) * DIM + cq * 16 + k * 8;
                const float* e2p = emb + (size_t)((ii[j] >> 9) & 511) * DIM + cq * 16 + k * 8;
                float4 p0 = *(const float4*)(e1p), p1 = *(const float4*)(e1p + 4);
                float4 q0 = *(const float4*)(e2p), q1 = *(const float4*)(e2p + 4);
                float e1c[8] = {p0.x, p0.y, p0.z, p0.w, p1.x, p1.y, p1.z, p1.w};
                float e2c[8] = {q0.x, q0.y, q0.z, q0.w, q1.x, q1.y, q1.z, q1.w};
                #pragma unroll
                for (int c = 0; c < 8; ++c) {
                    float zc = (j == 0) ? v[c].x : (j == 1) ? v[c].y
                             : (j == 2) ? v[c].z : v[c].w;
                    d1[j] = fmaf(zc, e1c[c], d1[j]);
                    d2[j] = fmaf(zc, e2c[c], d2[j]);
                }
            }
        }
        float2* part = (float2*)Ash;           // Ash dead after K-loop + barrier
        #pragma unroll
        for (int j = 0; j < 4; ++j)
            part[(4 * g + j) * 9 + cq] = make_float2(d1[j], d2[j]);
    }
    __syncthreads();
    if (t < 128) {
        int ii = ish[t];
        int i1 = ii & 511, i2 = (ii >> 9) & 511;
        const float2* pr = (const float2*)Ash + (size_t)t * 9;
        float d1 = 0.f, d2 = 0.f;
        #pragma unroll
        for (int cq = 0; cq < 8; ++cq) {
            float2 pv = pr[cq];
            d1 += pv.x;
            d2 += pv.y;
        }
        float s1 = fmaf(-2.f, d1, esq[i1]);
        float s2 = fmaf(-2.f, d2, esq[i2]);
        bool take2 = (s2 < s1) || (s2 == s1 && i2 < i1);   // lex (s,k)
        ish[t] = take2 ? i2 : i1;              // final winner (flagged fixed below)
        // EXACT full-screen (validated v10): winner can escape {i1,i2} only if
        // s* >= m3 - EPS1 -> resolve in-block.
        if (fminf(s1, s2) >= msh[t] - EPS1) {
            int q = atomicAdd(&bcnt, 1);
            ((int*)&mB1[1][0])[q] = t;         // flist overlay (mB1[1] dead)
        }
    }
    __syncthreads();

    // ---- amortized in-block full rescan: chunks of 4 flags, ONE codebook pass
    // per chunk. zstage lives at Ash+10240 (pair partials end at 9216, dead).
    {
        int nf = bcnt;
        float (*zst)[128] = (float (*)[128])(Ash + 10240);   // 4 x 128 fp32
        const int* fl = (const int*)&mB1[1][0];
        for (int f0 = 0; f0 < nf; f0 += 4) {
            int nc = nf - f0; if (nc > 4) nc = 4;
            {   // stage up to 4 flagged z-rows: 2 scattered dwords per thread
                #pragma unroll
                for (int h = 0; h < 2; ++h) {
                    int E = t + h * 256;       // 0..511: row = E>>7, ch = E&127
                    int r = E >> 7, ch = E & 127;
                    int rr = r < nc ? r : nc - 1;            // clamp: dup benign
                    int p = fl[f0 + rr];
                    zst[r][ch] = z[(size_t)bb * DIM * HWX + (size_t)ch * HWX + (hw0 + p)];
                }
            }
            __syncthreads();
            // one codebook pass: thread owns codes t and t+256, 4 rows broadcast
            const float* ea = emb + (size_t)t * DIM;
            const float* eb = emb + (size_t)(t + 256) * DIM;
            float da[4] = {0.f, 0.f, 0.f, 0.f};
            float db[4] = {0.f, 0.f, 0.f, 0.f};
            #pragma unroll 4
            for (int c4 = 0; c4 < 32; ++c4) {  // per-dot order identical to refine
                float4 va = *(const float4*)(ea + c4 * 4);
                float4 vb = *(const float4*)(eb + c4 * 4);
                #pragma unroll
                for (int r = 0; r < 4; ++r) {
                    float4 zv = *(const float4*)&zst[r][c4 * 4];   // LDS broadcast
                    da[r] = fmaf(zv.x, va.x, da[r]); da[r] = fmaf(zv.y, va.y, da[r]);
                    da[r] = fmaf(zv.z, va.z, da[r]); da[r] = fmaf(zv.w, va.w, da[r]);
                    db[r] = fmaf(zv.x, vb.x, db[r]); db[r] = fmaf(zv.y, vb.y, db[r]);
                    db[r] = fmaf(zv.z, vb.z, db[r]); db[r] = fmaf(zv.w, vb.w, db[r]);
                }
            }
            float esa = esq[t], esb = esq[t + 256];
            #pragma unroll
            for (int r = 0; r < 4; ++r) {
                float sa = fmaf(-2.f, da[r], esa);
                float sb = fmaf(-2.f, db[r], esb);
                float bs = sa; int bk = t;
                if (sb < bs) { bs = sb; bk = t + 256; }   // t < t+256: strict <
                #pragma unroll
                for (int d = 1; d < 64; d <<= 1) {        // width-64 lex butterfly
                    float os = __shfl_xor(bs, d, 64);
                    int   ok = __shfl_xor(bk, d, 64);
                    bool take = (os < bs) || (os == bs && ok < bk);
                    bs = take ? os : bs;
                    bk = take ? ok : bk;
                }
                if (lane == 0) {
                    mB2[0][r * 4 + wave] = bs;            // reduce scratch (dead)
                    ((int*)&mB2[1][0])[r * 4 + wave] = bk;
                }
            }
            __syncthreads();
            if (t < nc) {                                 // merge 4 waves, row t
                float s = mB2[0][t * 4]; int k = ((int*)&mB2[1][0])[t * 4];
                #pragma unroll
                for (int w = 1; w < 4; ++w) {
                    float s2 = mB2[0][t * 4 + w]; int k2 = ((int*)&mB2[1][0])[t * 4 + w];
                    bool take = (s2 < s) || (s2 == s && k2 < k);
                    s = take ? s2 : s;
                    k = take ? k2 : k;
                }
                ish[fl[f0 + t]] = k;                      // exact winner
            }
            __syncthreads();   // zst/scratch reusable; ish visible to epilogue
        }
    }

    // ---- epilogue: 4 positions x 16 channels per thread; gather 4 winner rows
    {
        int g = t & 31, cq = t >> 5;
        int hw = hw0 + 4 * g;
        int i0 = ish[4 * g + 0], i1v = ish[4 * g + 1];
        int i2 = ish[4 * g + 2], i3 = ish[4 * g + 3];
        const float4* e0 = (const float4*)(emb + (size_t)i0 * DIM) + cq * 4;
        const float4* e1 = (const float4*)(emb + (size_t)i1v * DIM) + cq * 4;
        const float4* e2 = (const float4*)(emb + (size_t)i2 * DIM) + cq * 4;
        const float4* e3 = (const float4*)(emb + (size_t)i3 * DIM) + cq * 4;
        float* ob = out + (size_t)bb * DIM * HWX + (size_t)cq * 16 * HWX + hw;
        #pragma unroll
        for (int cc = 0; cc < 4; ++cc) {
            float4 r0 = e0[cc], r1 = e1[cc], r2 = e2[cc], r3 = e3[cc];
            *(float4*)(ob + (size_t)(4 * cc + 0) * HWX) = (float4){r0.x, r1.x, r2.x, r3.x};
            *(float4*)(ob + (size_t)(4 * cc + 1) * HWX) = (float4){r0.y, r1.y, r2.y, r3.y};
            *(float4*)(ob + (size_t)(4 * cc + 2) * HWX) = (float4){r0.z, r1.z, r2.z, r3.z};
            *(float4*)(ob + (size_t)(4 * cc + 3) * HWX) = (float4){r0.w, r1.w, r2.w, r3.w};
        }
    }
}

// ---------------- legacy fallback (round-1, verified) ----------------
__global__ void esq_kernel(const float* __restrict__ emb, float* __restrict__ e_sq) {
    int k = blockIdx.x * blockDim.x + threadIdx.x;
    if (k < NUM_EMB) {
        const float4* row = (const float4*)(emb + k * DIM);
        float s0 = 0.f, s1 = 0.f, s2 = 0.f, s3 = 0.f;
        #pragma unroll
        for (int c = 0; c < DIM / 4; ++c) {
            float4 v = row[c];
            s0 = fmaf(v.x, v.x, s0); s1 = fmaf(v.y, v.y, s1);
            s2 = fmaf(v.z, v.z, s2); s3 = fmaf(v.w, v.w, s3);
        }
        e_sq[k] = (s0 + s1) + (s2 + s3);
    }
}

__global__ __launch_bounds__(256) void vq_kernel(const float* __restrict__ z,
                                                 const float* __restrict__ emb,
                                                 const float* __restrict__ e_sq,
                                                 float* __restrict__ out) {
    int n = blockIdx.x * 256 + threadIdx.x;
    int b = n >> 12, hw = n & 4095;
    const float* zb = z + (size_t)b * DIM * HWX + hw;
    float zr[DIM];
    #pragma unroll
    for (int c = 0; c < DIM; ++c) zr[c] = zb[(size_t)c * HWX];
    float best = FLT_MAX; int besti = 0;
    for (int k = 0; k < NUM_EMB; ++k) {
        const float4* er = (const float4*)(emb + k * DIM);
        float d0 = 0.f, d1 = 0.f, d2 = 0.f, d3 = 0.f;
        #pragma unroll
        for (int c = 0; c < DIM / 4; ++c) {
            float4 e = er[c];
            d0 = fmaf(zr[4 * c + 0], e.x, d0);
            d1 = fmaf(zr[4 * c + 1], e.y, d1);
            d2 = fmaf(zr[4 * c + 2], e.z, d2);
            d3 = fmaf(zr[4 * c + 3], e.w, d3);
        }
        float s = e_sq[k] - 2.f * ((d0 + d1) + (d2 + d3));
        if (s < best) { best = s; besti = k; }
    }
    float* ob = out + (size_t)b * DIM * HWX + hw;
    const float4* sel = (const float4*)(emb + (size_t)besti * DIM);
    #pragma unroll
    for (int c4 = 0; c4 < DIM / 4; ++c4) {
        float4 v = sel[c4];
        ob[(size_t)(4 * c4 + 0) * HWX] = v.x;
        ob[(size_t)(4 * c4 + 1) * HWX] = v.y;
        ob[(size_t)(4 * c4 + 2) * HWX] = v.z;
        ob[(size_t)(4 * c4 + 3) * HWX] = v.w;
    }
}

extern "C" void kernel_launch(void* const* d_in, const int* in_sizes, int n_in,
                              void* d_out, int out_size, void* d_ws, size_t ws_size,
                              hipStream_t stream) {
    const float* z   = (const float*)d_in[0];   // (32,128,64,64) fp32
    const float* emb = (const float*)d_in[1];   // (512,128) fp32
    float* out = (float*)d_out;

    if (ws_size < WS_NEED) {
        // fallback: verified round-1 path
        float* e_sq = (float*)d_ws;
        esq_kernel<<<(NUM_EMB + 255) / 256, 256, 0, stream>>>(emb, e_sq);
        vq_kernel<<<NPOS / 256, 256, 0, stream>>>(z, emb, e_sq, out);
        return;
    }

    char* ws = (char*)d_ws;
    _Float16* e16 = (_Float16*)(ws + WS_E16);
    float*    esq = (float*)(ws + WS_ESQ);

    prep_kernel<<<2, 256, 0, stream>>>(emb, e16, esq);
    gemm_argmin<<<NPOS / 128, 256, 0, stream>>>(z, e16, esq, emb, out);
}

// Round 9
// 188.716 us; speedup vs baseline: 1.0038x; 1.0038x over previous
//
#include <hip/hip_runtime.h>
#include <float.h>

#define NUM_EMB 512
#define DIM     128
#define HWX     4096          // 64*64 spatial per batch
#define NPOS    (32 * 4096)   // 131072 positions
#define EPS1    0.175f        // per-SCORE half of the validated 0.35 comparison budget

// ---------------- workspace layout (bytes) ----------------
#define WS_E16   ((size_t)0)                    // 512*128 fp16 = 131072
#define WS_ESQ   ((size_t)131072)               // 512 fp32     = 2048
#define WS_NEED  ((size_t)133120)

using half8 = __attribute__((ext_vector_type(8))) _Float16;
using f32x4 = __attribute__((ext_vector_type(4))) float;

// ---------------- prep: e16[k][c], exact e_sq ----------------
__global__ void prep_kernel(const float* __restrict__ emb, _Float16* __restrict__ e16,
                            float* __restrict__ esq) {
    int k = blockIdx.x * blockDim.x + threadIdx.x;
    if (k < NUM_EMB) {
        const float4* row = (const float4*)(emb + (size_t)k * DIM);
        _Float16* dst = e16 + (size_t)k * DIM;
        float s0 = 0.f, s1 = 0.f, s2 = 0.f, s3 = 0.f;
        #pragma unroll
        for (int c = 0; c < DIM / 4; ++c) {
            float4 v = row[c];
            s0 = fmaf(v.x, v.x, s0);
            s1 = fmaf(v.y, v.y, s1);
            s2 = fmaf(v.z, v.z, s2);
            s3 = fmaf(v.w, v.w, s3);
            dst[4 * c + 0] = (_Float16)v.x;
            dst[4 * c + 1] = (_Float16)v.y;
            dst[4 * c + 2] = (_Float16)v.z;
            dst[4 * c + 3] = (_Float16)v.w;
        }
        esq[k] = (s0 + s1) + (s2 + s3);   // identical math to round-1 (verified exact)
    }
}

// ---------------- gemm v13: v12 with PHASE REORDER --------------------------
// v11/v12 showed the rescan cost (~17 us) is pass-count-INDEPENDENT: it sits
// on the block critical path between the pair phase and the epilogue, so the
// 65 MB output store drain waits behind a TA-serialized compute phase. v13:
// (1) provisional epilogue FIRST (pair winners; stores fire-and-forget),
// (2) chunked rescan (unchanged v12 math) fixes ish for flagged positions,
// (3) patch: re-write only the flagged rows (ordering vs provisional stores
// guaranteed by the rescan's __syncthreads vmcnt drains; nf==0 => no patch).
// All validated math (K-loop, top-3, screen, pair, rescan dots) bit-identical.
__global__ __launch_bounds__(256) void gemm_argmin(const float* __restrict__ z,
                                                   const _Float16* __restrict__ e16,
                                                   const float* __restrict__ esq,
                                                   const float* __restrict__ emb,
                                                   float* __restrict__ out) {
    __shared__ __align__(16) char Ash[128 * 272];   // A tile; pair-partials; zstage
    __shared__ float mB1[2][128];                   // ranking; mB1[1] reused as flist
    __shared__ float mB2[2][128];                   // ranking; reused as reduce scratch
    __shared__ float mB3[2][128];
    __shared__ float msh[128];                      // packed m3 per position
    __shared__ int   ish[128];
    __shared__ int   bcnt;

    int t = threadIdx.x;
    int lane = t & 63, wave = t >> 6;
    int wm = wave & 1, wn = wave >> 1;
    int quad = lane >> 4, l15 = lane & 15;
    int n0 = blockIdx.x * 128;
    int bb = n0 >> 12;
    int hw0 = n0 & 4095;          // block-aligned: same batch, contiguous 128 hw

    if (t == 0) bcnt = 0;

    // ---- prologue: 4 consecutive positions x 16 channels per thread, dwordx4
    {
        int g = t & 31, cq = t >> 5;
        int hw = hw0 + 4 * g;
        const float* zp = z + (size_t)bb * DIM * HWX + (size_t)cq * 16 * HWX + hw;
        char* arow0 = Ash + (4 * g) * 272;
        int xr = g & 7;                         // = (row>>2)&7 for rows 4g..4g+3
        #pragma unroll
        for (int k = 0; k < 2; ++k) {           // two 8-channel chunks
            float4 v[8];
            #pragma unroll
            for (int c = 0; c < 8; ++c)
                v[c] = *(const float4*)(zp + (size_t)(k * 8 + c) * HWX);
            int slotb = ((2 * cq + k) ^ xr) * 16;   // swizzled 16B slot
            #pragma unroll
            for (int j = 0; j < 4; ++j) {       // register 4x4 transpose -> row j
                half8 hv;
                #pragma unroll
                for (int c = 0; c < 8; ++c) {
                    float f = (j == 0) ? v[c].x : (j == 1) ? v[c].y
                            : (j == 2) ? v[c].z : v[c].w;
                    hv[c] = (_Float16)f;
                }
                *(half8*)(arow0 + j * 272 + slotb) = hv;
            }
        }
    }
    __syncthreads();   // the ONLY barrier before the ranking phase

    float b1[16], b2[16], b3[16];
    #pragma unroll
    for (int s = 0; s < 16; ++s) { b1[s] = 3.0e38f; b2[s] = 3.0e38f; b3[s] = 3.0e38f; }

    // A-fragment base: row = wm*64 + mt*16 + l15; swizzle folds to lane-const
    const char* abase = Ash + (wm * 64 + l15) * 272 + (quad ^ (l15 >> 2)) * 16;
    const char* ebase = (const char*)e16 + ((size_t)(wn * 32 + l15) << 8) + quad * 16;
    const float* eqb  = esq + wn * 32 + l15;

    for (int tile = 0; tile < 8; ++tile) {
        // ---- B fragments: 8 dwordx4 from L2-hot e16, issued together
        half8 bf[2][4];
        {
            const char* eb = ebase + (size_t)tile * 64 * 256;
            #pragma unroll
            for (int nt = 0; nt < 2; ++nt)
                #pragma unroll
                for (int kc = 0; kc < 4; ++kc)
                    bf[nt][kc] = *(const half8*)(eb + nt * 4096 + kc * 64);
        }
        float es0 = eqb[tile * 64];
        float es1 = eqb[tile * 64 + 16];

        f32x4 acc[4][2];
        #pragma unroll
        for (int mt = 0; mt < 4; ++mt)
            #pragma unroll
            for (int nt = 0; nt < 2; ++nt)
                acc[mt][nt] = (f32x4){0.f, 0.f, 0.f, 0.f};

        #pragma unroll
        for (int kc = 0; kc < 4; ++kc) {
            half8 af[4];
            #pragma unroll
            for (int mt = 0; mt < 4; ++mt)
                af[mt] = *(const half8*)(abase + mt * (16 * 272) + ((kc ^ (mt & 1)) * 64));
            #pragma unroll
            for (int mt = 0; mt < 4; ++mt)
                #pragma unroll
                for (int nt = 0; nt < 2; ++nt)
                    acc[mt][nt] = __builtin_amdgcn_mfma_f32_16x16x32_f16(af[mt], bf[nt][kc], acc[mt][nt], 0, 0, 0);
        }

        // ---- packed top-3: ~8 VALU/score, index rides in the low 9 bits
        #pragma unroll
        for (int nt = 0; nt < 2; ++nt) {
            unsigned code = (unsigned)(tile * 64 + wn * 32 + nt * 16 + l15);
            float es = nt ? es1 : es0;
            #pragma unroll
            for (int mt = 0; mt < 4; ++mt)
                #pragma unroll
                for (int r = 0; r < 4; ++r) {
                    int s = mt * 4 + r;
                    float sc = fmaf(-2.0f, acc[mt][nt][r], es);
                    float p = __uint_as_float((__float_as_uint(sc) & 0xFFFFFE00u) | code);
                    float t1 = fmaxf(b1[s], p);       // displaced from level 1
                    b1[s] = fminf(b1[s], p);
                    float t2 = fmaxf(b2[s], t1);      // displaced from level 2
                    b2[s] = fminf(b2[s], t1);
                    b3[s] = fminf(b3[s], t2);
                }
        }
    }

    // ---- butterfly top-3 merge across the 16 lanes (l15) sharing each position
    #pragma unroll
    for (int d = 1; d < 16; d <<= 1) {
        #pragma unroll
        for (int s = 0; s < 16; ++s) {
            float o1 = __shfl_xor(b1[s], d, 64);
            float o2 = __shfl_xor(b2[s], d, 64);
            float o3 = __shfl_xor(b3[s], d, 64);
            float u1 = fmaxf(b1[s], o1);
            b1[s] = fminf(b1[s], o1);
            float l2 = fminf(b2[s], o2);
            float w  = fmaxf(u1, l2);
            b2[s] = fminf(u1, l2);
            b3[s] = fminf(fminf(b3[s], o3), w);
        }
    }
    if (l15 == 0) {
        #pragma unroll
        for (int s = 0; s < 16; ++s) {
            int m = wm * 64 + (s >> 2) * 16 + quad * 4 + (s & 3);
            mB1[wn][m] = b1[s];
            mB2[wn][m] = b2[s];
            mB3[wn][m] = b3[s];
        }
    }
    __syncthreads();
    if (t < 128) {
        float a1 = mB1[0][t], c1 = mB1[1][t];
        float a2 = mB2[0][t], c2 = mB2[1][t];
        float a3 = mB3[0][t], c3 = mB3[1][t];
        float u1 = fmaxf(a1, c1);
        float m1 = fminf(a1, c1);
        float l2 = fminf(a2, c2);
        float m2 = fminf(u1, l2);
        float m3 = fminf(fminf(a3, c3), fmaxf(u1, l2));
        int ix1 = (int)(__float_as_uint(m1) & 511u);
        int ix2 = (int)(__float_as_uint(m2) & 511u);
        ish[t] = ix1 | (ix2 << 9);             // packed candidates for the pair phase
        msh[t] = m3;                           // packed 3rd-best for the exact screen
    }
    __syncthreads();

    // ---- fused pair phase: coalesced z re-read (L2/L3-hot), exact fp32 dots
    // with e_{i1}, e_{i2}; partials to a 9-float2-stride LDS overlay on Ash.
    {
        int g = t & 31, cq = t >> 5;
        int hw = hw0 + 4 * g;
        const float* zp = z + (size_t)bb * DIM * HWX + (size_t)cq * 16 * HWX + hw;
        int ii[4];
        #pragma unroll
        for (int j = 0; j < 4; ++j) ii[j] = ish[4 * g + j];
        float d1[4] = {0.f, 0.f, 0.f, 0.f};
        float d2[4] = {0.f, 0.f, 0.f, 0.f};
        #pragma unroll
        for (int k = 0; k < 2; ++k) {
            float4 v[8];
            #pragma unroll
            for (int c = 0; c < 8; ++c)
                v[c] = *(const float4*)(zp + (size_t)(k * 8 + c) * HWX);
            #pragma unroll
            for (int j = 0; j < 4; ++j) {
                const float* e1p = emb + (size_t)(ii[j] & 511) * DIM + cq * 16 + k * 8;
                const float* e2p = emb + (size_t)((ii[j] >> 9) & 511) * DIM + cq * 16 + k * 8;
                float4 p0 = *(const float4*)(e1p), p1 = *(const float4*)(e1p + 4);
                float4 q0 = *(const float4*)(e2p), q1 = *(const float4*)(e2p + 4);
                float e1c[8] = {p0.x, p0.y, p0.z, p0.w, p1.x, p1.y, p1.z, p1.w};
                float e2c[8] = {q0.x, q0.y, q0.z, q0.w, q1.x, q1.y, q1.z, q1.w};
                #pragma unroll
                for (int c = 0; c < 8; ++c) {
                    float zc = (j == 0) ? v[c].x : (j == 1) ? v[c].y
                             : (j == 2) ? v[c].z : v[c].w;
                    d1[j] = fmaf(zc, e1c[c], d1[j]);
                    d2[j] = fmaf(zc, e2c[c], d2[j]);
                }
            }
        }
        float2* part = (float2*)Ash;           // Ash dead after K-loop + barrier
        #pragma unroll
        for (int j = 0; j < 4; ++j)
            part[(4 * g + j) * 9 + cq] = make_float2(d1[j], d2[j]);
    }
    __syncthreads();
    if (t < 128) {
        int ii = ish[t];
        int i1 = ii & 511, i2 = (ii >> 9) & 511;
        const float2* pr = (const float2*)Ash + (size_t)t * 9;
        float d1 = 0.f, d2 = 0.f;
        #pragma unroll
        for (int cq = 0; cq < 8; ++cq) {
            float2 pv = pr[cq];
            d1 += pv.x;
            d2 += pv.y;
        }
        float s1 = fmaf(-2.f, d1, esq[i1]);
        float s2 = fmaf(-2.f, d2, esq[i2]);
        bool take2 = (s2 < s1) || (s2 == s1 && i2 < i1);   // lex (s,k)
        ish[t] = take2 ? i2 : i1;              // provisional winner (flagged patched)
        // EXACT full-screen (validated v10): winner can escape {i1,i2} only if
        // s* >= m3 - EPS1 -> resolve in-block after the provisional epilogue.
        if (fminf(s1, s2) >= msh[t] - EPS1) {
            int q = atomicAdd(&bcnt, 1);
            ((int*)&mB1[1][0])[q] = t;         // flist overlay (mB1[1] dead)
        }
    }
    __syncthreads();

    // ---- PROVISIONAL epilogue (moved before rescan): 4 pos x 16 ch per thread.
    // Stores are fire-and-forget and drain under the rescan's TA/VALU phase.
    {
        int g = t & 31, cq = t >> 5;
        int hw = hw0 + 4 * g;
        int i0 = ish[4 * g + 0], i1v = ish[4 * g + 1];
        int i2 = ish[4 * g + 2], i3 = ish[4 * g + 3];
        const float4* e0 = (const float4*)(emb + (size_t)i0 * DIM) + cq * 4;
        const float4* e1 = (const float4*)(emb + (size_t)i1v * DIM) + cq * 4;
        const float4* e2 = (const float4*)(emb + (size_t)i2 * DIM) + cq * 4;
        const float4* e3 = (const float4*)(emb + (size_t)i3 * DIM) + cq * 4;
        float* ob = out + (size_t)bb * DIM * HWX + (size_t)cq * 16 * HWX + hw;
        #pragma unroll
        for (int cc = 0; cc < 4; ++cc) {
            float4 r0 = e0[cc], r1 = e1[cc], r2 = e2[cc], r3 = e3[cc];
            *(float4*)(ob + (size_t)(4 * cc + 0) * HWX) = (float4){r0.x, r1.x, r2.x, r3.x};
            *(float4*)(ob + (size_t)(4 * cc + 1) * HWX) = (float4){r0.y, r1.y, r2.y, r3.y};
            *(float4*)(ob + (size_t)(4 * cc + 2) * HWX) = (float4){r0.z, r1.z, r2.z, r3.z};
            *(float4*)(ob + (size_t)(4 * cc + 3) * HWX) = (float4){r0.w, r1.w, r2.w, r3.w};
        }
    }

    // ---- amortized in-block full rescan: chunks of 4 flags, ONE codebook pass
    // per chunk. zstage lives at Ash+10240 (pair partials end at 9216, dead).
    {
        int nf = bcnt;
        float (*zst)[128] = (float (*)[128])(Ash + 10240);   // 4 x 128 fp32
        const int* fl = (const int*)&mB1[1][0];
        for (int f0 = 0; f0 < nf; f0 += 4) {
            int nc = nf - f0; if (nc > 4) nc = 4;
            {   // stage up to 4 flagged z-rows: 2 scattered dwords per thread
                #pragma unroll
                for (int h = 0; h < 2; ++h) {
                    int E = t + h * 256;       // 0..511: row = E>>7, ch = E&127
                    int r = E >> 7, ch = E & 127;
                    int rr = r < nc ? r : nc - 1;            // clamp: dup benign
                    int p = fl[f0 + rr];
                    zst[r][ch] = z[(size_t)bb * DIM * HWX + (size_t)ch * HWX + (hw0 + p)];
                }
            }
            __syncthreads();
            // one codebook pass: thread owns codes t and t+256, 4 rows broadcast
            const float* ea = emb + (size_t)t * DIM;
            const float* eb = emb + (size_t)(t + 256) * DIM;
            float da[4] = {0.f, 0.f, 0.f, 0.f};
            float db[4] = {0.f, 0.f, 0.f, 0.f};
            #pragma unroll 4
            for (int c4 = 0; c4 < 32; ++c4) {  // per-dot order identical to refine
                float4 va = *(const float4*)(ea + c4 * 4);
                float4 vb = *(const float4*)(eb + c4 * 4);
                #pragma unroll
                for (int r = 0; r < 4; ++r) {
                    float4 zv = *(const float4*)&zst[r][c4 * 4];   // LDS broadcast
                    da[r] = fmaf(zv.x, va.x, da[r]); da[r] = fmaf(zv.y, va.y, da[r]);
                    da[r] = fmaf(zv.z, va.z, da[r]); da[r] = fmaf(zv.w, va.w, da[r]);
                    db[r] = fmaf(zv.x, vb.x, db[r]); db[r] = fmaf(zv.y, vb.y, db[r]);
                    db[r] = fmaf(zv.z, vb.z, db[r]); db[r] = fmaf(zv.w, vb.w, db[r]);
                }
            }
            float esa = esq[t], esb = esq[t + 256];
            #pragma unroll
            for (int r = 0; r < 4; ++r) {
                float sa = fmaf(-2.f, da[r], esa);
                float sb = fmaf(-2.f, db[r], esb);
                float bs = sa; int bk = t;
                if (sb < bs) { bs = sb; bk = t + 256; }   // t < t+256: strict <
                #pragma unroll
                for (int d = 1; d < 64; d <<= 1) {        // width-64 lex butterfly
                    float os = __shfl_xor(bs, d, 64);
                    int   ok = __shfl_xor(bk, d, 64);
                    bool take = (os < bs) || (os == bs && ok < bk);
                    bs = take ? os : bs;
                    bk = take ? ok : bk;
                }
                if (lane == 0) {
                    mB2[0][r * 4 + wave] = bs;            // reduce scratch (dead)
                    ((int*)&mB2[1][0])[r * 4 + wave] = bk;
                }
            }
            __syncthreads();
            if (t < nc) {                                 // merge 4 waves, row t
                float s = mB2[0][t * 4]; int k = ((int*)&mB2[1][0])[t * 4];
                #pragma unroll
                for (int w = 1; w < 4; ++w) {
                    float s2 = mB2[0][t * 4 + w]; int k2 = ((int*)&mB2[1][0])[t * 4 + w];
                    bool take = (s2 < s) || (s2 == s && k2 < k);
                    s = take ? s2 : s;
                    k = take ? k2 : k;
                }
                ish[fl[f0 + t]] = k;                      // exact winner
            }
            __syncthreads();   // zst/scratch reusable; ish visible below
        }

        // ---- patch: re-write only the flagged rows with corrected winners.
        // Ordering vs the provisional stores is guaranteed: the rescan's
        // barriers drained vmcnt after the provisional epilogue (nf>0 here).
        for (int f = 0; f < nf; ++f) {
            int p = fl[f];
            int kk = ish[p];
            if (t < 128)
                out[(size_t)bb * DIM * HWX + (size_t)t * HWX + (hw0 + p)]
                    = emb[(size_t)kk * DIM + t];
        }
    }
}

// ---------------- legacy fallback (round-1, verified) ----------------
__global__ void esq_kernel(const float* __restrict__ emb, float* __restrict__ e_sq) {
    int k = blockIdx.x * blockDim.x + threadIdx.x;
    if (k < NUM_EMB) {
        const float4* row = (const float4*)(emb + k * DIM);
        float s0 = 0.f, s1 = 0.f, s2 = 0.f, s3 = 0.f;
        #pragma unroll
        for (int c = 0; c < DIM / 4; ++c) {
            float4 v = row[c];
            s0 = fmaf(v.x, v.x, s0); s1 = fmaf(v.y, v.y, s1);
            s2 = fmaf(v.z, v.z, s2); s3 = fmaf(v.w, v.w, s3);
        }
        e_sq[k] = (s0 + s1) + (s2 + s3);
    }
}

__global__ __launch_bounds__(256) void vq_kernel(const float* __restrict__ z,
                                                 const float* __restrict__ emb,
                                                 const float* __restrict__ e_sq,
                                                 float* __restrict__ out) {
    int n = blockIdx.x * 256 + threadIdx.x;
    int b = n >> 12, hw = n & 4095;
    const float* zb = z + (size_t)b * DIM * HWX + hw;
    float zr[DIM];
    #pragma unroll
    for (int c = 0; c < DIM; ++c) zr[c] = zb[(size_t)c * HWX];
    float best = FLT_MAX; int besti = 0;
    for (int k = 0; k < NUM_EMB; ++k) {
        const float4* er = (const float4*)(emb + k * DIM);
        float d0 = 0.f, d1 = 0.f, d2 = 0.f, d3 = 0.f;
        #pragma unroll
        for (int c = 0; c < DIM / 4; ++c) {
            float4 e = er[c];
            d0 = fmaf(zr[4 * c + 0], e.x, d0);
            d1 = fmaf(zr[4 * c + 1], e.y, d1);
            d2 = fmaf(zr[4 * c + 2], e.z, d2);
            d3 = fmaf(zr[4 * c + 3], e.w, d3);
        }
        float s = e_sq[k] - 2.f * ((d0 + d1) + (d2 + d3));
        if (s < best) { best = s; besti = k; }
    }
    float* ob = out + (size_t)b * DIM * HWX + hw;
    const float4* sel = (const float4*)(emb + (size_t)besti * DIM);
    #pragma unroll
    for (int c4 = 0; c4 < DIM / 4; ++c4) {
        float4 v = sel[c4];
        ob[(size_t)(4 * c4 + 0) * HWX] = v.x;
        ob[(size_t)(4 * c4 + 1) * HWX] = v.y;
        ob[(size_t)(4 * c4 + 2) * HWX] = v.z;
        ob[(size_t)(4 * c4 + 3) * HWX] = v.w;
    }
}

extern "C" void kernel_launch(void* const* d_in, const int* in_sizes, int n_in,
                              void* d_out, int out_size, void* d_ws, size_t ws_size,
                              hipStream_t stream) {
    const float* z   = (const float*)d_in[0];   // (32,128,64,64) fp32
    const float* emb = (const float*)d_in[1];   // (512,128) fp32
    float* out = (float*)d_out;

    if (ws_size < WS_NEED) {
        // fallback: verified round-1 path
        float* e_sq = (float*)d_ws;
        esq_kernel<<<(NUM_EMB + 255) / 256, 256, 0, stream>>>(emb, e_sq);
        vq_kernel<<<NPOS / 256, 256, 0, stream>>>(z, emb, e_sq, out);
        return;
    }

    char* ws = (char*)d_ws;
    _Float16* e16 = (_Float16*)(ws + WS_E16);
    float*    esq = (float*)(ws + WS_ESQ);

    prep_kernel<<<2, 256, 0, stream>>>(emb, e16, esq);
    gemm_argmin<<<NPOS / 128, 256, 0, stream>>>(z, e16, esq, emb, out);
}